// Round 6
// baseline (317.495 us; speedup 1.0000x reference)
//
#include <hip/hip_runtime.h>
#include <hip/hip_bf16.h>

typedef unsigned short u16;
typedef unsigned int   u32;

#define NP     4096
#define NCH    131072
#define HBASE  393216            // rel region = 131072*3
#define CLBASE 33947648          // HBASE + 131072*256

// ws layout (bytes)
#define WS_W2F   0               // 512 frags * 1KB  (W2: frag_id = nb*16 + kc)
#define WS_W3F   524288          // 256 frags * 1KB  (W3: frag_id = nb*16 + kc)
#define WS_F1    1048576         // [4096][512] f32

using bf16x8 = __attribute__((ext_vector_type(8))) short;
using f32x4  = __attribute__((ext_vector_type(4))) float;

__device__ inline u32 pk2(float a, float b) {
  __hip_bfloat162 h = __float22bfloat162_rn(make_float2(a, b));
  return *reinterpret_cast<u32*>(&h);
}

// swizzle: 16B-slot index for (row r, bf16-col c); bijective per row
__device__ inline int swz(int r, int cg) {        // cg = col>>3
  return cg ^ (r & 7) ^ ((r >> 3) & 3);
}

// ================= K1: f1+rel / W-prep / cluster, merged ====================
// blocks [0,256): f1+rel   [256,384): W2   [384,448): W3   [448,512): cluster
__global__ __launch_bounds__(512, 2) void k_pre(const float* __restrict__ in_feats,
                                                const float* __restrict__ Wd,
                                                const float* __restrict__ bd,
                                                const float* __restrict__ W1,
                                                const float* __restrict__ b1,
                                                const float* __restrict__ W2,
                                                const float* __restrict__ W3,
                                                u16* __restrict__ w2f,
                                                u16* __restrict__ w3f,
                                                float* __restrict__ F1,
                                                float* __restrict__ out) {
  __shared__ __align__(16) char smem[69504];
  int b = blockIdx.x, tid = threadIdx.x;

  if (b < 256) {
    // ---- f1: F1 = feat @ W1a + b1 (MFMA) ; rel: neigh @ Wd + bd (fp32) ----
    u16*   sh_a = (u16*)smem;                    // [16][256] bf16 swizzled, 8KB
    float* b1s  = (float*)(smem + 8192);         // 2KB
    float* wdT  = (float*)(smem + 10240);        // [96][132] f32, 50688B
    float* ne   = (float*)(smem + 60928);        // [16][128] f32, 8KB
    float* bds  = (float*)(smem + 69120);        // 384B
    int p0 = b * 16, lane = tid & 63, w = tid >> 6;
    b1s[tid] = b1[tid];
    if (tid < 96) bds[tid] = bd[tid];
    {   // neigh rows (cols 0..128) fp32
      int r = tid >> 5, k4 = (tid & 31) * 4;
      *(float4*)(ne + r * 128 + k4) = *(const float4*)(in_feats + (p0 + r) * 384 + k4);
    }
    {   // feature rows (cols 128..384) -> bf16 swizzled
      int r = tid >> 5, k0 = (tid & 31) * 8;
      const float4 v0 = *(const float4*)(in_feats + (p0 + r) * 384 + 128 + k0);
      const float4 v1 = *(const float4*)(in_feats + (p0 + r) * 384 + 128 + k0 + 4);
      uint4 o;
      o.x = pk2(v0.x, v0.y); o.y = pk2(v0.z, v0.w);
      o.z = pk2(v1.x, v1.y); o.w = pk2(v1.z, v1.w);
      int slot = (k0 >> 3) ^ (r & 7);
      *(uint4*)(sh_a + r * 256 + slot * 8) = o;
    }
    {   // Wd[k][c] -> wdT[c][k] (pitch 132)
#pragma unroll
      for (int i = 0; i < 6; ++i) {
        int idx = i * 512 + tid;                 // 3072 float4s, c-major
        int k = idx / 24, c4 = (idx % 24) * 4;
        const float4 v = *(const float4*)(Wd + k * 96 + c4);
        wdT[(c4 + 0) * 132 + k] = v.x;
        wdT[(c4 + 1) * 132 + k] = v.y;
        wdT[(c4 + 2) * 132 + k] = v.z;
        wdT[(c4 + 3) * 132 + k] = v.w;
      }
    }
    __syncthreads();
    // ---- rel: 3 outputs/thread, float4 dots from LDS ----
#pragma unroll
    for (int j = 0; j < 3; ++j) {
      int u = j * 512 + tid;
      int p = u / 96, c = u - p * 96;
      const float4* nep = (const float4*)(ne + p * 128);
      const float4* wp  = (const float4*)(wdT + c * 132);
      float4 a4 = {0.f, 0.f, 0.f, 0.f};
#pragma unroll 8
      for (int kq = 0; kq < 32; ++kq) {
        const float4 av = nep[kq], bv = wp[kq];
        a4.x += av.x * bv.x; a4.y += av.y * bv.y;
        a4.z += av.z * bv.z; a4.w += av.w * bv.w;
      }
      out[(p0 + p) * 96 + c] = bds[c] + ((a4.x + a4.y) + (a4.z + a4.w));
    }
    // ---- f1 MFMA (B-frags direct from W1 f32) ----
    f32x4 acc[4];
#pragma unroll
    for (int i = 0; i < 4; ++i) acc[i] = f32x4{0.f, 0.f, 0.f, 0.f};
    int col = lane & 15, q8 = (lane >> 4) * 8;
#pragma unroll
    for (int kc = 0; kc < 8; ++kc) {
      int slot = ((kc * 32 + q8) >> 3) ^ (col & 7);
      bf16x8 a = *(const bf16x8*)(sh_a + col * 256 + slot * 8);
#pragma unroll
      for (int nf = 0; nf < 4; ++nf) {
        const float* wp = W1 + (kc * 32 + q8) * 512 + (w * 4 + nf) * 16 + col;
        float v0 = wp[0],      v1 = wp[512],  v2 = wp[1024], v3 = wp[1536];
        float v4 = wp[2048],   v5 = wp[2560], v6 = wp[3072], v7 = wp[3584];
        union { bf16x8 v; u32 u[4]; } uu;
        uu.u[0] = pk2(v0, v1); uu.u[1] = pk2(v2, v3);
        uu.u[2] = pk2(v4, v5); uu.u[3] = pk2(v6, v7);
        acc[nf] = __builtin_amdgcn_mfma_f32_16x16x32_bf16(a, uu.v, acc[nf], 0, 0, 0);
      }
    }
    int rb = (lane >> 4) * 4;
#pragma unroll
    for (int nf = 0; nf < 4; ++nf) {
      int n = w * 64 + nf * 16 + col;
#pragma unroll
      for (int i = 0; i < 4; ++i)
        F1[(p0 + rb + i) * 512 + n] = acc[nf][i] + b1s[n];
    }
  } else if (b < 448) {
    // ---------------- W2/W3 -> bf16 fragment layout (2 tiles/block) ---------
    float (*tile)[32][33] = (float (*)[32][33])smem;   // 8448B
    int h = tid >> 8, t = tid & 255;
    const float* src; u16* dst; int pitchN, g;
    if (b < 384) { g = (b - 256) * 2 + h; src = W2; dst = w2f; pitchN = 512; }
    else         { g = (b - 384) * 2 + h; src = W3; dst = w3f; pitchN = 256; }
    int kt = g & 15, nt = g >> 4;
    {
      int kk = t >> 3, n4 = (t & 7) * 4;
      const float4 v = *(const float4*)(src + (kt * 32 + kk) * pitchN + nt * 32 + n4);
      tile[h][kk][n4 + 0] = v.x; tile[h][kk][n4 + 1] = v.y;
      tile[h][kk][n4 + 2] = v.z; tile[h][kk][n4 + 3] = v.w;
    }
    __syncthreads();
    {
      int s = t >> 1, half = t & 1, fr = s >> 6, l = s & 63;
      int n_l = fr * 16 + (l & 15);
      int k_l = (l >> 4) * 8 + half * 4;
      uint2 o;
      o.x = pk2(tile[h][k_l + 0][n_l], tile[h][k_l + 1][n_l]);
      o.y = pk2(tile[h][k_l + 2][n_l], tile[h][k_l + 3][n_l]);
      int frag_id = (nt * 2 + fr) * 16 + kt;
      *(uint2*)(dst + frag_id * 512 + l * 8 + half * 4) = o;
    }
  } else {
    // ---------------- cluster ids ------------------------------------------
    int idx = ((b - 448) * 512 + tid) * 4;
    float c = (float)(idx >> 5);
    float* p = out + CLBASE + idx;
    __builtin_nontemporal_store(c, p + 0);
    __builtin_nontemporal_store(c, p + 1);
    __builtin_nontemporal_store(c, p + 2);
    __builtin_nontemporal_store(c, p + 3);
  }
}

// ====== K2: fused h1-build + GEMM2 + GEMM3 (M=64, 2 blocks/CU) ==============
__global__ __launch_bounds__(512, 4) void k_main(const float* __restrict__ W1,
                                                 const float* __restrict__ b2,
                                                 const float* __restrict__ b3,
                                                 const u16* __restrict__ w2f,
                                                 const u16* __restrict__ w3f,
                                                 const float* __restrict__ F1,
                                                 float* __restrict__ out) {
  int blk = blockIdx.x;                          // 2048 blocks, 2 parents each
  int tid = threadIdx.x, lane = tid & 63, w = tid >> 6;
  __shared__ u16 sh_h[64 * 512];                 // h1 then h2, swizzled
  __shared__ float f1s[1024], w1bs[1536], b2s[512], b3s[256], rels[192];

  f1s[tid]       = F1[blk * 1024 + tid];
  f1s[tid + 512] = F1[blk * 1024 + 512 + tid];
  w1bs[tid]        = W1[131072 + tid];           // W1 rows 256..258
  w1bs[tid + 512]  = W1[131072 + 512 + tid];
  w1bs[tid + 1024] = W1[131072 + 1024 + tid];
  b2s[tid] = b2[tid];
  if (tid < 256) b3s[tid] = b3[tid];
  if (tid < 192) rels[tid] = out[blk * 192 + tid];
  __syncthreads();

  // ---- build h1 (64 x 512) into LDS as bf16; 16B writes ----
  {
    int r = tid & 31, g = tid >> 5;              // g in 0..15
#pragma unroll
    for (int rr = 0; rr < 64; rr += 32) {
      int row = rr + r, pp = rr >> 5;
      float r0 = rels[row * 3 + 0], r1 = rels[row * 3 + 1], r2 = rels[row * 3 + 2];
#pragma unroll
      for (int gg = 0; gg < 4; ++gg) {
        int c8 = g * 8 + gg * 128;
        const float4 fa = *(const float4*)(f1s + pp * 512 + c8);
        const float4 fb = *(const float4*)(f1s + pp * 512 + c8 + 4);
        const float4 wa0 = *(const float4*)(w1bs + c8);
        const float4 wb0 = *(const float4*)(w1bs + c8 + 4);
        const float4 wa1 = *(const float4*)(w1bs + 512 + c8);
        const float4 wb1 = *(const float4*)(w1bs + 512 + c8 + 4);
        const float4 wa2 = *(const float4*)(w1bs + 1024 + c8);
        const float4 wb2 = *(const float4*)(w1bs + 1024 + c8 + 4);
        float v0 = fmaxf(fa.x + r0 * wa0.x + r1 * wa1.x + r2 * wa2.x, 0.f);
        float v1 = fmaxf(fa.y + r0 * wa0.y + r1 * wa1.y + r2 * wa2.y, 0.f);
        float v2 = fmaxf(fa.z + r0 * wa0.z + r1 * wa1.z + r2 * wa2.z, 0.f);
        float v3 = fmaxf(fa.w + r0 * wa0.w + r1 * wa1.w + r2 * wa2.w, 0.f);
        float v4 = fmaxf(fb.x + r0 * wb0.x + r1 * wb1.x + r2 * wb2.x, 0.f);
        float v5 = fmaxf(fb.y + r0 * wb0.y + r1 * wb1.y + r2 * wb2.y, 0.f);
        float v6 = fmaxf(fb.z + r0 * wb0.z + r1 * wb1.z + r2 * wb2.z, 0.f);
        float v7 = fmaxf(fb.w + r0 * wb0.w + r1 * wb1.w + r2 * wb2.w, 0.f);
        uint4 o;
        o.x = pk2(v0, v1); o.y = pk2(v2, v3);
        o.z = pk2(v4, v5); o.w = pk2(v6, v7);
        *(uint4*)(sh_h + row * 512 + swz(row, c8 >> 3) * 8) = o;
      }
    }
  }
  __syncthreads();

  int col = lane & 15, q8 = (lane >> 4) * 8;

  // ---- GEMM2: h2 = relu(h1 @ W2 + b2); prefetched B-frags ----
  f32x4 acc2[4][4];
#pragma unroll
  for (int mf = 0; mf < 4; ++mf)
#pragma unroll
    for (int nf = 0; nf < 4; ++nf) acc2[mf][nf] = f32x4{0.f, 0.f, 0.f, 0.f};
  {
    const u16* w2p = w2f + (size_t)(w * 4 * 16) * 512 + lane * 8;
    bf16x8 bufA[4], bufB[4];
#pragma unroll
    for (int nf = 0; nf < 4; ++nf) bufA[nf] = *(const bf16x8*)(w2p + nf * 16 * 512);
#pragma unroll 2
    for (int kc = 0; kc < 16; ++kc) {
      const bf16x8* cur = (kc & 1) ? bufB : bufA;
      bf16x8* nxt = (kc & 1) ? bufA : bufB;
      if (kc < 15) {
#pragma unroll
        for (int nf = 0; nf < 4; ++nf)
          nxt[nf] = *(const bf16x8*)(w2p + (nf * 16 + kc + 1) * 512);
      }
      int cb = (kc * 32 + q8) >> 3;
#pragma unroll
      for (int mf = 0; mf < 4; ++mf) {
        int row = mf * 16 + col;
        bf16x8 a = *(const bf16x8*)(sh_h + row * 512 + swz(row, cb) * 8);
#pragma unroll
        for (int nf = 0; nf < 4; ++nf)
          acc2[mf][nf] = __builtin_amdgcn_mfma_f32_16x16x32_bf16(a, cur[nf], acc2[mf][nf], 0, 0, 0);
      }
    }
  }
  __syncthreads();   // all h1 reads done

  // ---- h2 -> LDS (relu + bf16) ----
  {
    int rq = (lane >> 4) * 4;
#pragma unroll
    for (int mf = 0; mf < 4; ++mf)
#pragma unroll
      for (int nf = 0; nf < 4; ++nf) {
        int n = w * 64 + nf * 16 + col, cg = n >> 3, n7 = n & 7;
        float bv = b2s[n];
#pragma unroll
        for (int i = 0; i < 4; i += 2) {
          int r0 = mf * 16 + rq + i, r1 = r0 + 1;
          u32 p = pk2(fmaxf(acc2[mf][nf][i] + bv, 0.f),
                      fmaxf(acc2[mf][nf][i + 1] + bv, 0.f));
          sh_h[r0 * 512 + swz(r0, cg) * 8 + n7] = (u16)(p & 0xffff);
          sh_h[r1 * 512 + swz(r1, cg) * 8 + n7] = (u16)(p >> 16);
        }
      }
  }
  __syncthreads();

  // ---- GEMM3: h3 = relu(h2 @ W3 + b3); prefetched B-frags ----
  f32x4 acc3[4][2];
#pragma unroll
  for (int mf = 0; mf < 4; ++mf)
#pragma unroll
    for (int nf = 0; nf < 2; ++nf) acc3[mf][nf] = f32x4{0.f, 0.f, 0.f, 0.f};
  {
    const u16* w3p = w3f + (size_t)(w * 2 * 16) * 512 + lane * 8;
    bf16x8 bufA[2], bufB[2];
#pragma unroll
    for (int nf = 0; nf < 2; ++nf) bufA[nf] = *(const bf16x8*)(w3p + nf * 16 * 512);
#pragma unroll 2
    for (int kc = 0; kc < 16; ++kc) {
      const bf16x8* cur = (kc & 1) ? bufB : bufA;
      bf16x8* nxt = (kc & 1) ? bufA : bufB;
      if (kc < 15) {
#pragma unroll
        for (int nf = 0; nf < 2; ++nf)
          nxt[nf] = *(const bf16x8*)(w3p + (nf * 16 + kc + 1) * 512);
      }
      int cb = (kc * 32 + q8) >> 3;
#pragma unroll
      for (int mf = 0; mf < 4; ++mf) {
        int row = mf * 16 + col;
        bf16x8 a = *(const bf16x8*)(sh_h + row * 512 + swz(row, cb) * 8);
#pragma unroll
        for (int nf = 0; nf < 2; ++nf)
          acc3[mf][nf] = __builtin_amdgcn_mfma_f32_16x16x32_bf16(a, cur[nf], acc3[mf][nf], 0, 0, 0);
      }
    }
  }

  // ---- epilogue: write h (non-temporal) ----
  {
    int rq = (lane >> 4) * 4;
#pragma unroll
    for (int mf = 0; mf < 4; ++mf)
#pragma unroll
      for (int nf = 0; nf < 2; ++nf) {
        int n = w * 32 + nf * 16 + col;
        float bv = b3s[n];
#pragma unroll
        for (int i = 0; i < 4; ++i) {
          int r = mf * 16 + rq + i;
          float v = fmaxf(acc3[mf][nf][i] + bv, 0.f);
          __builtin_nontemporal_store(v, out + HBASE + (blk * 64 + r) * 256 + n);
        }
      }
  }
}

extern "C" void kernel_launch(void* const* d_in, const int* in_sizes, int n_in,
                              void* d_out, int out_size, void* d_ws, size_t ws_size,
                              hipStream_t stream) {
  const float* in_feats = (const float*)d_in[0];
  const float* Wd = (const float*)d_in[1];
  const float* bd = (const float*)d_in[2];
  const float* W1 = (const float*)d_in[3];
  const float* b1 = (const float*)d_in[4];
  const float* W2 = (const float*)d_in[5];
  const float* b2 = (const float*)d_in[6];
  const float* W3 = (const float*)d_in[7];
  const float* b3 = (const float*)d_in[8];
  float* out = (float*)d_out;
  char* ws = (char*)d_ws;
  u16*   w2f = (u16*)(ws + WS_W2F);
  u16*   w3f = (u16*)(ws + WS_W3F);
  float* F1  = (float*)(ws + WS_F1);

  k_pre<<<512, 512, 0, stream>>>(in_feats, Wd, bd, W1, b1, W2, W3, w2f, w3f, F1, out);
  k_main<<<2048, 512, 0, stream>>>(W1, b2, b3, w2f, w3f, F1, out);
}

// Round 7
// 288.234 us; speedup vs baseline: 1.1015x; 1.1015x over previous
//
#include <hip/hip_runtime.h>
#include <hip/hip_bf16.h>

typedef unsigned short u16;
typedef unsigned int   u32;

#define NP     4096
#define NCH    131072
#define HBASE  393216            // rel region = 131072*3
#define CLBASE 33947648          // HBASE + 131072*256

// ws layout (bytes)
#define WS_W2F   0               // 512 frags * 1KB  (W2: frag_id = (w*4+nf)*16 + kc)
#define WS_W3F   524288          // 256 frags * 1KB  (W3: frag_id = (w*2+nf)*16 + kc)
#define WS_F1    1048576         // [4096][512] f32

using bf16x8 = __attribute__((ext_vector_type(8))) short;
using f32x4  = __attribute__((ext_vector_type(4))) float;

__device__ inline u32 pk2(float a, float b) {
  __hip_bfloat162 h = __float22bfloat162_rn(make_float2(a, b));
  return *reinterpret_cast<u32*>(&h);
}
__device__ inline float bflo(u32 u) { union { u32 x; float f; } v; v.x = u << 16;        return v.f; }
__device__ inline float bfhi(u32 u) { union { u32 x; float f; } v; v.x = u & 0xffff0000u; return v.f; }

// swizzle for full h2 tile: 16B-slot index for (row r, col-group cg)
__device__ inline int swz(int r, int cg) {
  return cg ^ (r & 7) ^ ((r >> 3) & 3);
}

// ================= K1: f1+rel / W-prep / cluster, merged (as R5) ============
__global__ __launch_bounds__(512, 2) void k_pre(const float* __restrict__ in_feats,
                                                const float* __restrict__ Wd,
                                                const float* __restrict__ bd,
                                                const float* __restrict__ W1,
                                                const float* __restrict__ b1,
                                                const float* __restrict__ W2,
                                                const float* __restrict__ W3,
                                                u16* __restrict__ w2f,
                                                u16* __restrict__ w3f,
                                                float* __restrict__ F1,
                                                float* __restrict__ out) {
  __shared__ __align__(16) char smem[69504];
  int b = blockIdx.x, tid = threadIdx.x;

  if (b < 256) {
    u16*   sh_a = (u16*)smem;
    float* b1s  = (float*)(smem + 8192);
    float* wdT  = (float*)(smem + 10240);        // [96][132]
    float* ne   = (float*)(smem + 60928);        // [16][128]
    float* bds  = (float*)(smem + 69120);
    int p0 = b * 16, lane = tid & 63, w = tid >> 6;
    b1s[tid] = b1[tid];
    if (tid < 96) bds[tid] = bd[tid];
    {
      int r = tid >> 5, k4 = (tid & 31) * 4;
      *(float4*)(ne + r * 128 + k4) = *(const float4*)(in_feats + (p0 + r) * 384 + k4);
    }
    {
      int r = tid >> 5, k0 = (tid & 31) * 8;
      const float4 v0 = *(const float4*)(in_feats + (p0 + r) * 384 + 128 + k0);
      const float4 v1 = *(const float4*)(in_feats + (p0 + r) * 384 + 128 + k0 + 4);
      uint4 o;
      o.x = pk2(v0.x, v0.y); o.y = pk2(v0.z, v0.w);
      o.z = pk2(v1.x, v1.y); o.w = pk2(v1.z, v1.w);
      int slot = (k0 >> 3) ^ (r & 7);
      *(uint4*)(sh_a + r * 256 + slot * 8) = o;
    }
    {
#pragma unroll
      for (int i = 0; i < 6; ++i) {
        int idx = i * 512 + tid;
        int k = idx / 24, c4 = (idx % 24) * 4;
        const float4 v = *(const float4*)(Wd + k * 96 + c4);
        wdT[(c4 + 0) * 132 + k] = v.x;
        wdT[(c4 + 1) * 132 + k] = v.y;
        wdT[(c4 + 2) * 132 + k] = v.z;
        wdT[(c4 + 3) * 132 + k] = v.w;
      }
    }
    __syncthreads();
#pragma unroll
    for (int j = 0; j < 3; ++j) {
      int u = j * 512 + tid;
      int p = u / 96, c = u - p * 96;
      const float4* nep = (const float4*)(ne + p * 128);
      const float4* wp  = (const float4*)(wdT + c * 132);
      float4 a4 = {0.f, 0.f, 0.f, 0.f};
#pragma unroll 8
      for (int kq = 0; kq < 32; ++kq) {
        const float4 av = nep[kq], bv = wp[kq];
        a4.x += av.x * bv.x; a4.y += av.y * bv.y;
        a4.z += av.z * bv.z; a4.w += av.w * bv.w;
      }
      out[(p0 + p) * 96 + c] = bds[c] + ((a4.x + a4.y) + (a4.z + a4.w));
    }
    f32x4 acc[4];
#pragma unroll
    for (int i = 0; i < 4; ++i) acc[i] = f32x4{0.f, 0.f, 0.f, 0.f};
    int col = lane & 15, q8 = (lane >> 4) * 8;
#pragma unroll
    for (int kc = 0; kc < 8; ++kc) {
      int slot = ((kc * 32 + q8) >> 3) ^ (col & 7);
      bf16x8 a = *(const bf16x8*)(sh_a + col * 256 + slot * 8);
#pragma unroll
      for (int nf = 0; nf < 4; ++nf) {
        const float* wp = W1 + (kc * 32 + q8) * 512 + (w * 4 + nf) * 16 + col;
        float v0 = wp[0],      v1 = wp[512],  v2 = wp[1024], v3 = wp[1536];
        float v4 = wp[2048],   v5 = wp[2560], v6 = wp[3072], v7 = wp[3584];
        union { bf16x8 v; u32 u[4]; } uu;
        uu.u[0] = pk2(v0, v1); uu.u[1] = pk2(v2, v3);
        uu.u[2] = pk2(v4, v5); uu.u[3] = pk2(v6, v7);
        acc[nf] = __builtin_amdgcn_mfma_f32_16x16x32_bf16(a, uu.v, acc[nf], 0, 0, 0);
      }
    }
    int rb = (lane >> 4) * 4;
#pragma unroll
    for (int nf = 0; nf < 4; ++nf) {
      int n = w * 64 + nf * 16 + col;
#pragma unroll
      for (int i = 0; i < 4; ++i)
        F1[(p0 + rb + i) * 512 + n] = acc[nf][i] + b1s[n];
    }
  } else if (b < 448) {
    float (*tile)[32][33] = (float (*)[32][33])smem;
    int h = tid >> 8, t = tid & 255;
    const float* src; u16* dst; int pitchN, g;
    if (b < 384) { g = (b - 256) * 2 + h; src = W2; dst = w2f; pitchN = 512; }
    else         { g = (b - 384) * 2 + h; src = W3; dst = w3f; pitchN = 256; }
    int kt = g & 15, nt = g >> 4;
    {
      int kk = t >> 3, n4 = (t & 7) * 4;
      const float4 v = *(const float4*)(src + (kt * 32 + kk) * pitchN + nt * 32 + n4);
      tile[h][kk][n4 + 0] = v.x; tile[h][kk][n4 + 1] = v.y;
      tile[h][kk][n4 + 2] = v.z; tile[h][kk][n4 + 3] = v.w;
    }
    __syncthreads();
    {
      int s = t >> 1, half = t & 1, fr = s >> 6, l = s & 63;
      int n_l = fr * 16 + (l & 15);
      int k_l = (l >> 4) * 8 + half * 4;
      uint2 o;
      o.x = pk2(tile[h][k_l + 0][n_l], tile[h][k_l + 1][n_l]);
      o.y = pk2(tile[h][k_l + 2][n_l], tile[h][k_l + 3][n_l]);
      int frag_id = (nt * 2 + fr) * 16 + kt;
      *(uint2*)(dst + frag_id * 512 + l * 8 + half * 4) = o;
    }
  } else {
    int idx = ((b - 448) * 512 + tid) * 4;
    float c = (float)(idx >> 5);
    float* p = out + CLBASE + idx;
    __builtin_nontemporal_store(c, p + 0);
    __builtin_nontemporal_store(c, p + 1);
    __builtin_nontemporal_store(c, p + 2);
    __builtin_nontemporal_store(c, p + 3);
  }
}

// ====== K2: slice-fused h1 + GEMM2 + repack + GEMM3 (M=128, 1 blk/CU) =======
// LDS map (bytes):
//   sh_h2   [128][512] bf16 swizzled          0      .. 131072
//   sbuf    2 x [128][32] bf16 granule-swz    131072 .. 147456
//   f1b     [4][512] bf16                     147456 .. 151552
//   w1bs    [3][512] f32                      151552 .. 157696
//   b2s     [512] f32                         157696 .. 159744
//   b3s     [256] f32                         159744 .. 160768
//   rels    [384] f32                         160768 .. 162304
__global__ __launch_bounds__(512, 2) void k_main(const float* __restrict__ W1,
                                                 const float* __restrict__ b2,
                                                 const float* __restrict__ b3,
                                                 const u16* __restrict__ w2f,
                                                 const u16* __restrict__ w3f,
                                                 const float* __restrict__ F1,
                                                 float* __restrict__ out) {
  __shared__ __align__(16) char smem[162304];
  u16*   sh_h2 = (u16*)smem;
  u16*   sb0   = (u16*)(smem + 131072);
  u16*   sb1   = (u16*)(smem + 139264);
  u16*   f1b   = (u16*)(smem + 147456);
  float* w1bs  = (float*)(smem + 151552);
  float* b2s   = (float*)(smem + 157696);
  float* b3s   = (float*)(smem + 159744);
  float* rels  = (float*)(smem + 160768);

  int blk = blockIdx.x;
  int tid = threadIdx.x, lane = tid & 63, w = tid >> 6;
  int col = lane & 15, q = lane >> 4, q8 = q * 8;

  // ---- init loads ----
  {
    const float4 v = *(const float4*)(F1 + blk * 2048 + tid * 4);
    uint2 o; o.x = pk2(v.x, v.y); o.y = pk2(v.z, v.w);
    *(uint2*)(f1b + tid * 4) = o;
  }
  w1bs[tid]        = W1[131072 + tid];           // W1 rows 256..258
  w1bs[tid + 512]  = W1[131072 + 512 + tid];
  w1bs[tid + 1024] = W1[131072 + 1024 + tid];
  b2s[tid] = b2[tid];
  if (tid < 256) b3s[tid] = b3[tid];
  if (tid < 384) rels[tid] = out[blk * 384 + tid];
  __syncthreads();

  // ---- slice builder: h1[:, ks*32 .. ks*32+32) -> sb (granule-XOR swz) ----
  auto BUILD = [&](int ks, u16* sb) {
    int row = tid >> 2, g = tid & 3;
    int colG = ks * 32 + g * 8;
    int p = row >> 5;
    float r0 = rels[row * 3 + 0], r1 = rels[row * 3 + 1], r2 = rels[row * 3 + 2];
    const uint4 fu = *(const uint4*)(f1b + p * 512 + colG);
    const float4 wa0 = *(const float4*)(w1bs + colG);
    const float4 wb0 = *(const float4*)(w1bs + colG + 4);
    const float4 wa1 = *(const float4*)(w1bs + 512 + colG);
    const float4 wb1 = *(const float4*)(w1bs + 512 + colG + 4);
    const float4 wa2 = *(const float4*)(w1bs + 1024 + colG);
    const float4 wb2 = *(const float4*)(w1bs + 1024 + colG + 4);
    float v0 = fmaxf(bflo(fu.x) + r0 * wa0.x + r1 * wa1.x + r2 * wa2.x, 0.f);
    float v1 = fmaxf(bfhi(fu.x) + r0 * wa0.y + r1 * wa1.y + r2 * wa2.y, 0.f);
    float v2 = fmaxf(bflo(fu.y) + r0 * wa0.z + r1 * wa1.z + r2 * wa2.z, 0.f);
    float v3 = fmaxf(bfhi(fu.y) + r0 * wa0.w + r1 * wa1.w + r2 * wa2.w, 0.f);
    float v4 = fmaxf(bflo(fu.z) + r0 * wb0.x + r1 * wb1.x + r2 * wb2.x, 0.f);
    float v5 = fmaxf(bfhi(fu.z) + r0 * wb0.y + r1 * wb1.y + r2 * wb2.y, 0.f);
    float v6 = fmaxf(bflo(fu.w) + r0 * wb0.z + r1 * wb1.z + r2 * wb2.z, 0.f);
    float v7 = fmaxf(bfhi(fu.w) + r0 * wb0.w + r1 * wb1.w + r2 * wb2.w, 0.f);
    uint4 o;
    o.x = pk2(v0, v1); o.y = pk2(v2, v3);
    o.z = pk2(v4, v5); o.w = pk2(v6, v7);
    int pg = g ^ ((row >> 1) & 3);
    *(uint4*)(sb + row * 32 + pg * 8) = o;
  };

  BUILD(0, sb0);
  __syncthreads();

  // ---- GEMM2 (slice-fused): h2 = relu(h1 @ W2 + b2) ----
  f32x4 acc2[8][4];
#pragma unroll
  for (int mf = 0; mf < 8; ++mf)
#pragma unroll
    for (int nf = 0; nf < 4; ++nf) acc2[mf][nf] = f32x4{0.f, 0.f, 0.f, 0.f};
  {
    const u16* w2p = w2f + (size_t)(w * 4 * 16) * 512 + lane * 8;
    bf16x8 bufA[4], bufB[4];
#pragma unroll
    for (int nf = 0; nf < 4; ++nf) bufA[nf] = *(const bf16x8*)(w2p + nf * 16 * 512);
    for (int kc = 0; kc < 16; ++kc) {
      const bf16x8* cur = (kc & 1) ? bufB : bufA;
      bf16x8* nxt = (kc & 1) ? bufA : bufB;
      u16* sbc = (kc & 1) ? sb1 : sb0;
      u16* sbn = (kc & 1) ? sb0 : sb1;
      if (kc < 15) {
#pragma unroll
        for (int nf = 0; nf < 4; ++nf)
          nxt[nf] = *(const bf16x8*)(w2p + (nf * 16 + kc + 1) * 512);
        BUILD(kc + 1, sbn);
      }
#pragma unroll
      for (int mf = 0; mf < 8; ++mf) {
        int r = mf * 16 + col;
        bf16x8 a = *(const bf16x8*)(sbc + r * 32 + ((q ^ ((r >> 1) & 3)) << 3));
#pragma unroll
        for (int nf = 0; nf < 4; ++nf)
          acc2[mf][nf] = __builtin_amdgcn_mfma_f32_16x16x32_bf16(a, cur[nf], acc2[mf][nf], 0, 0, 0);
      }
      __syncthreads();
    }
  }

  // ---- h2 -> LDS full tile (relu + bf16) ----
  {
    int rq = q * 4;
#pragma unroll
    for (int mf = 0; mf < 8; ++mf)
#pragma unroll
      for (int nf = 0; nf < 4; ++nf) {
        int n = w * 64 + nf * 16 + col, cg = n >> 3, n7 = n & 7;
        float bv = b2s[n];
#pragma unroll
        for (int i = 0; i < 4; i += 2) {
          int r0 = mf * 16 + rq + i, r1 = r0 + 1;
          u32 p = pk2(fmaxf(acc2[mf][nf][i] + bv, 0.f),
                      fmaxf(acc2[mf][nf][i + 1] + bv, 0.f));
          sh_h2[r0 * 512 + swz(r0, cg) * 8 + n7] = (u16)(p & 0xffff);
          sh_h2[r1 * 512 + swz(r1, cg) * 8 + n7] = (u16)(p >> 16);
        }
      }
  }
  __syncthreads();

  // ---- GEMM3: h3 = relu(h2 @ W3 + b3); barrier-free, prefetched ----
  f32x4 acc3[8][2];
#pragma unroll
  for (int mf = 0; mf < 8; ++mf)
#pragma unroll
    for (int nf = 0; nf < 2; ++nf) acc3[mf][nf] = f32x4{0.f, 0.f, 0.f, 0.f};
  {
    const u16* w3p = w3f + (size_t)(w * 2 * 16) * 512 + lane * 8;
    bf16x8 bufA[2], bufB[2];
#pragma unroll
    for (int nf = 0; nf < 2; ++nf) bufA[nf] = *(const bf16x8*)(w3p + nf * 16 * 512);
#pragma unroll 2
    for (int kc = 0; kc < 16; ++kc) {
      const bf16x8* cur = (kc & 1) ? bufB : bufA;
      bf16x8* nxt = (kc & 1) ? bufA : bufB;
      if (kc < 15) {
#pragma unroll
        for (int nf = 0; nf < 2; ++nf)
          nxt[nf] = *(const bf16x8*)(w3p + (nf * 16 + kc + 1) * 512);
      }
      int cb = (kc * 32 + q8) >> 3;
#pragma unroll
      for (int mf = 0; mf < 8; ++mf) {
        int r = mf * 16 + col;
        bf16x8 a = *(const bf16x8*)(sh_h2 + r * 512 + swz(r, cb) * 8);
#pragma unroll
        for (int nf = 0; nf < 2; ++nf)
          acc3[mf][nf] = __builtin_amdgcn_mfma_f32_16x16x32_bf16(a, cur[nf], acc3[mf][nf], 0, 0, 0);
      }
    }
  }

  // ---- epilogue ----
  {
    int rq = q * 4;
#pragma unroll
    for (int mf = 0; mf < 8; ++mf)
#pragma unroll
      for (int nf = 0; nf < 2; ++nf) {
        int n = w * 32 + nf * 16 + col;
        float bv = b3s[n];
#pragma unroll
        for (int i = 0; i < 4; ++i) {
          int r = mf * 16 + rq + i;
          float v = fmaxf(acc3[mf][nf][i] + bv, 0.f);
          __builtin_nontemporal_store(v, out + HBASE + (blk * 128 + r) * 256 + n);
        }
      }
  }
}

extern "C" void kernel_launch(void* const* d_in, const int* in_sizes, int n_in,
                              void* d_out, int out_size, void* d_ws, size_t ws_size,
                              hipStream_t stream) {
  const float* in_feats = (const float*)d_in[0];
  const float* Wd = (const float*)d_in[1];
  const float* bd = (const float*)d_in[2];
  const float* W1 = (const float*)d_in[3];
  const float* b1 = (const float*)d_in[4];
  const float* W2 = (const float*)d_in[5];
  const float* b2 = (const float*)d_in[6];
  const float* W3 = (const float*)d_in[7];
  const float* b3 = (const float*)d_in[8];
  float* out = (float*)d_out;
  char* ws = (char*)d_ws;
  u16*   w2f = (u16*)(ws + WS_W2F);
  u16*   w3f = (u16*)(ws + WS_W3F);
  float* F1  = (float*)(ws + WS_F1);

  k_pre<<<512, 512, 0, stream>>>(in_feats, Wd, bd, W1, b1, W2, W3, w2f, w3f, F1, out);
  k_main<<<1024, 512, 0, stream>>>(W1, b2, b3, w2f, w3f, F1, out);
}

// Round 8
// 267.123 us; speedup vs baseline: 1.1886x; 1.0790x over previous
//
#include <hip/hip_runtime.h>
#include <hip/hip_bf16.h>

typedef unsigned short u16;
typedef unsigned int   u32;

#define NP     4096
#define NCH    131072
#define HBASE  393216            // rel region = 131072*3
#define CLBASE 33947648          // HBASE + 131072*256

// ws layout (bytes)
#define WS_W2F   0               // 512 frags * 1KB  (W2: frag_id = nb*16 + kc)
#define WS_W3F   524288          // 256 frags * 1KB  (W3: frag_id = nb*16 + kc)
#define WS_F1    1048576         // [4096][512] f32

using bf16x8 = __attribute__((ext_vector_type(8))) short;
using f32x4  = __attribute__((ext_vector_type(4))) float;

__device__ inline u32 pk2(float a, float b) {
  __hip_bfloat162 h = __float22bfloat162_rn(make_float2(a, b));
  return *reinterpret_cast<u32*>(&h);
}

// swizzle: 16B-slot index for (row r, col-group cg); bijective per row
__device__ inline int swz(int r, int cg) {
  return cg ^ (r & 7) ^ ((r >> 3) & 3);
}

// ================= K1: f1+rel / W-prep / cluster, merged (as R5) ============
__global__ __launch_bounds__(512, 2) void k_pre(const float* __restrict__ in_feats,
                                                const float* __restrict__ Wd,
                                                const float* __restrict__ bd,
                                                const float* __restrict__ W1,
                                                const float* __restrict__ b1,
                                                const float* __restrict__ W2,
                                                const float* __restrict__ W3,
                                                u16* __restrict__ w2f,
                                                u16* __restrict__ w3f,
                                                float* __restrict__ F1,
                                                float* __restrict__ out) {
  __shared__ __align__(16) char smem[69504];
  int b = blockIdx.x, tid = threadIdx.x;

  if (b < 256) {
    u16*   sh_a = (u16*)smem;
    float* b1s  = (float*)(smem + 8192);
    float* wdT  = (float*)(smem + 10240);        // [96][132]
    float* ne   = (float*)(smem + 60928);        // [16][128]
    float* bds  = (float*)(smem + 69120);
    int p0 = b * 16, lane = tid & 63, w = tid >> 6;
    b1s[tid] = b1[tid];
    if (tid < 96) bds[tid] = bd[tid];
    {
      int r = tid >> 5, k4 = (tid & 31) * 4;
      *(float4*)(ne + r * 128 + k4) = *(const float4*)(in_feats + (p0 + r) * 384 + k4);
    }
    {
      int r = tid >> 5, k0 = (tid & 31) * 8;
      const float4 v0 = *(const float4*)(in_feats + (p0 + r) * 384 + 128 + k0);
      const float4 v1 = *(const float4*)(in_feats + (p0 + r) * 384 + 128 + k0 + 4);
      uint4 o;
      o.x = pk2(v0.x, v0.y); o.y = pk2(v0.z, v0.w);
      o.z = pk2(v1.x, v1.y); o.w = pk2(v1.z, v1.w);
      int slot = (k0 >> 3) ^ (r & 7);
      *(uint4*)(sh_a + r * 256 + slot * 8) = o;
    }
    {
#pragma unroll
      for (int i = 0; i < 6; ++i) {
        int idx = i * 512 + tid;
        int k = idx / 24, c4 = (idx % 24) * 4;
        const float4 v = *(const float4*)(Wd + k * 96 + c4);
        wdT[(c4 + 0) * 132 + k] = v.x;
        wdT[(c4 + 1) * 132 + k] = v.y;
        wdT[(c4 + 2) * 132 + k] = v.z;
        wdT[(c4 + 3) * 132 + k] = v.w;
      }
    }
    __syncthreads();
#pragma unroll
    for (int j = 0; j < 3; ++j) {
      int u = j * 512 + tid;
      int p = u / 96, c = u - p * 96;
      const float4* nep = (const float4*)(ne + p * 128);
      const float4* wp  = (const float4*)(wdT + c * 132);
      float4 a4 = {0.f, 0.f, 0.f, 0.f};
#pragma unroll 8
      for (int kq = 0; kq < 32; ++kq) {
        const float4 av = nep[kq], bv = wp[kq];
        a4.x += av.x * bv.x; a4.y += av.y * bv.y;
        a4.z += av.z * bv.z; a4.w += av.w * bv.w;
      }
      out[(p0 + p) * 96 + c] = bds[c] + ((a4.x + a4.y) + (a4.z + a4.w));
    }
    f32x4 acc[4];
#pragma unroll
    for (int i = 0; i < 4; ++i) acc[i] = f32x4{0.f, 0.f, 0.f, 0.f};
    int col = lane & 15, q8 = (lane >> 4) * 8;
#pragma unroll
    for (int kc = 0; kc < 8; ++kc) {
      int slot = ((kc * 32 + q8) >> 3) ^ (col & 7);
      bf16x8 a = *(const bf16x8*)(sh_a + col * 256 + slot * 8);
#pragma unroll
      for (int nf = 0; nf < 4; ++nf) {
        const float* wp = W1 + (kc * 32 + q8) * 512 + (w * 4 + nf) * 16 + col;
        float v0 = wp[0],      v1 = wp[512],  v2 = wp[1024], v3 = wp[1536];
        float v4 = wp[2048],   v5 = wp[2560], v6 = wp[3072], v7 = wp[3584];
        union { bf16x8 v; u32 u[4]; } uu;
        uu.u[0] = pk2(v0, v1); uu.u[1] = pk2(v2, v3);
        uu.u[2] = pk2(v4, v5); uu.u[3] = pk2(v6, v7);
        acc[nf] = __builtin_amdgcn_mfma_f32_16x16x32_bf16(a, uu.v, acc[nf], 0, 0, 0);
      }
    }
    int rb = (lane >> 4) * 4;
#pragma unroll
    for (int nf = 0; nf < 4; ++nf) {
      int n = w * 64 + nf * 16 + col;
#pragma unroll
      for (int i = 0; i < 4; ++i)
        F1[(p0 + rb + i) * 512 + n] = acc[nf][i] + b1s[n];
    }
  } else if (b < 448) {
    float (*tile)[32][33] = (float (*)[32][33])smem;
    int h = tid >> 8, t = tid & 255;
    const float* src; u16* dst; int pitchN, g;
    if (b < 384) { g = (b - 256) * 2 + h; src = W2; dst = w2f; pitchN = 512; }
    else         { g = (b - 384) * 2 + h; src = W3; dst = w3f; pitchN = 256; }
    int kt = g & 15, nt = g >> 4;
    {
      int kk = t >> 3, n4 = (t & 7) * 4;
      const float4 v = *(const float4*)(src + (kt * 32 + kk) * pitchN + nt * 32 + n4);
      tile[h][kk][n4 + 0] = v.x; tile[h][kk][n4 + 1] = v.y;
      tile[h][kk][n4 + 2] = v.z; tile[h][kk][n4 + 3] = v.w;
    }
    __syncthreads();
    {
      int s = t >> 1, half = t & 1, fr = s >> 6, l = s & 63;
      int n_l = fr * 16 + (l & 15);
      int k_l = (l >> 4) * 8 + half * 4;
      uint2 o;
      o.x = pk2(tile[h][k_l + 0][n_l], tile[h][k_l + 1][n_l]);
      o.y = pk2(tile[h][k_l + 2][n_l], tile[h][k_l + 3][n_l]);
      int frag_id = (nt * 2 + fr) * 16 + kt;
      *(uint2*)(dst + frag_id * 512 + l * 8 + half * 4) = o;
    }
  } else {
    int idx = ((b - 448) * 512 + tid) * 4;
    float c = (float)(idx >> 5);
    float* p = out + CLBASE + idx;
    __builtin_nontemporal_store(c, p + 0);
    __builtin_nontemporal_store(c, p + 1);
    __builtin_nontemporal_store(c, p + 2);
    __builtin_nontemporal_store(c, p + 3);
  }
}

// ====== K2: h1-build + GEMM2 + GEMM3; M=128, 1024 thr (16 waves, 4/SIMD) ====
__global__ __launch_bounds__(1024) void k_main(const float* __restrict__ W1,
                                               const float* __restrict__ b2,
                                               const float* __restrict__ b3,
                                               const u16* __restrict__ w2f,
                                               const u16* __restrict__ w3f,
                                               const float* __restrict__ F1,
                                               float* __restrict__ out) {
  int blk = blockIdx.x;
  int tid = threadIdx.x, lane = tid & 63, w = tid >> 6;  // w in 0..15
  int wm = w >> 3, wn = w & 7;                           // 2 M-groups x 8 N-groups
  int col = lane & 15, q = lane >> 4, q8 = q * 8;
  __shared__ u16 sh_h[128 * 512];      // h1 then h2, swizzled 16B slots
  __shared__ float f1s[2048], w1bs[1536], b2s[512], b3s[256], rels[384];

  // ---- init loads (1024 threads) ----
  if (tid < 512) *(float4*)(f1s + tid * 4) = *(const float4*)(F1 + blk * 2048 + tid * 4);
  if (tid < 768) *(float2*)(w1bs + tid * 2) = *(const float2*)(W1 + 131072 + tid * 2);
  if (tid < 512) b2s[tid] = b2[tid];
  if (tid >= 512 && tid < 768) b3s[tid - 512] = b3[tid - 512];
  if (tid >= 768 && tid < 1024) {
    float2 rv = *(const float2*)(out + blk * 384 + (tid - 768) * 2);  // rel smallbuf... wait 384 = 192*2
    rels[(tid - 768) * 2 + 0] = rv.x;
    rels[(tid - 768) * 2 + 1] = rv.y;
  }
  __syncthreads();

  // ---- build h1 (128 x 512) into LDS as bf16; 16B writes ----
  {
    int row = tid >> 3, g = tid & 7, pp = row >> 5;
    float r0 = rels[row * 3 + 0], r1 = rels[row * 3 + 1], r2 = rels[row * 3 + 2];
#pragma unroll
    for (int j = 0; j < 8; ++j) {
      int c8 = g * 8 + j * 64;
      const float4 fa = *(const float4*)(f1s + pp * 512 + c8);
      const float4 fb = *(const float4*)(f1s + pp * 512 + c8 + 4);
      const float4 wa0 = *(const float4*)(w1bs + c8);
      const float4 wb0 = *(const float4*)(w1bs + c8 + 4);
      const float4 wa1 = *(const float4*)(w1bs + 512 + c8);
      const float4 wb1 = *(const float4*)(w1bs + 512 + c8 + 4);
      const float4 wa2 = *(const float4*)(w1bs + 1024 + c8);
      const float4 wb2 = *(const float4*)(w1bs + 1024 + c8 + 4);
      float v0 = fmaxf(fa.x + r0 * wa0.x + r1 * wa1.x + r2 * wa2.x, 0.f);
      float v1 = fmaxf(fa.y + r0 * wa0.y + r1 * wa1.y + r2 * wa2.y, 0.f);
      float v2 = fmaxf(fa.z + r0 * wa0.z + r1 * wa1.z + r2 * wa2.z, 0.f);
      float v3 = fmaxf(fa.w + r0 * wa0.w + r1 * wa1.w + r2 * wa2.w, 0.f);
      float v4 = fmaxf(fb.x + r0 * wb0.x + r1 * wb1.x + r2 * wb2.x, 0.f);
      float v5 = fmaxf(fb.y + r0 * wb0.y + r1 * wb1.y + r2 * wb2.y, 0.f);
      float v6 = fmaxf(fb.z + r0 * wb0.z + r1 * wb1.z + r2 * wb2.z, 0.f);
      float v7 = fmaxf(fb.w + r0 * wb0.w + r1 * wb1.w + r2 * wb2.w, 0.f);
      uint4 o;
      o.x = pk2(v0, v1); o.y = pk2(v2, v3);
      o.z = pk2(v4, v5); o.w = pk2(v6, v7);
      *(uint4*)(sh_h + row * 512 + swz(row, c8 >> 3) * 8) = o;
    }
  }
  __syncthreads();

  // ---- GEMM2: h2 = relu(h1 @ W2 + b2); barrier-free, prefetched B ----
  f32x4 acc2[4][4];
#pragma unroll
  for (int mf = 0; mf < 4; ++mf)
#pragma unroll
    for (int nf = 0; nf < 4; ++nf) acc2[mf][nf] = f32x4{0.f, 0.f, 0.f, 0.f};
  {
    const u16* w2p = w2f + (size_t)(wn * 4 * 16) * 512 + lane * 8;
    bf16x8 bufA[4], bufB[4];
#pragma unroll
    for (int nf = 0; nf < 4; ++nf) bufA[nf] = *(const bf16x8*)(w2p + nf * 16 * 512);
#pragma unroll 2
    for (int kc = 0; kc < 16; ++kc) {
      const bf16x8* cur = (kc & 1) ? bufB : bufA;
      bf16x8* nxt = (kc & 1) ? bufA : bufB;
      if (kc < 15) {
#pragma unroll
        for (int nf = 0; nf < 4; ++nf)
          nxt[nf] = *(const bf16x8*)(w2p + (nf * 16 + kc + 1) * 512);
      }
      int cb = (kc * 32 + q8) >> 3;
#pragma unroll
      for (int mf = 0; mf < 4; ++mf) {
        int r = wm * 64 + mf * 16 + col;
        bf16x8 a = *(const bf16x8*)(sh_h + r * 512 + swz(r, cb) * 8);
#pragma unroll
        for (int nf = 0; nf < 4; ++nf)
          acc2[mf][nf] = __builtin_amdgcn_mfma_f32_16x16x32_bf16(a, cur[nf], acc2[mf][nf], 0, 0, 0);
      }
    }
  }
  __syncthreads();   // all h1 reads done

  // ---- h2 -> LDS (relu + bf16) ----
  {
    int rq = q * 4;
#pragma unroll
    for (int mf = 0; mf < 4; ++mf)
#pragma unroll
      for (int nf = 0; nf < 4; ++nf) {
        int n = wn * 64 + nf * 16 + col, cg = n >> 3, n7 = n & 7;
        float bv = b2s[n];
#pragma unroll
        for (int i = 0; i < 4; i += 2) {
          int r0 = wm * 64 + mf * 16 + rq + i, r1 = r0 + 1;
          u32 p = pk2(fmaxf(acc2[mf][nf][i] + bv, 0.f),
                      fmaxf(acc2[mf][nf][i + 1] + bv, 0.f));
          sh_h[r0 * 512 + swz(r0, cg) * 8 + n7] = (u16)(p & 0xffff);
          sh_h[r1 * 512 + swz(r1, cg) * 8 + n7] = (u16)(p >> 16);
        }
      }
  }
  __syncthreads();

  // ---- GEMM3: h3 = relu(h2 @ W3 + b3); barrier-free, prefetched B ----
  f32x4 acc3[4][2];
#pragma unroll
  for (int mf = 0; mf < 4; ++mf)
#pragma unroll
    for (int nf = 0; nf < 2; ++nf) acc3[mf][nf] = f32x4{0.f, 0.f, 0.f, 0.f};
  {
    const u16* w3p = w3f + (size_t)(wn * 2 * 16) * 512 + lane * 8;
    bf16x8 bufA[2], bufB[2];
#pragma unroll
    for (int nf = 0; nf < 2; ++nf) bufA[nf] = *(const bf16x8*)(w3p + nf * 16 * 512);
#pragma unroll 2
    for (int kc = 0; kc < 16; ++kc) {
      const bf16x8* cur = (kc & 1) ? bufB : bufA;
      bf16x8* nxt = (kc & 1) ? bufA : bufB;
      if (kc < 15) {
#pragma unroll
        for (int nf = 0; nf < 2; ++nf)
          nxt[nf] = *(const bf16x8*)(w3p + (nf * 16 + kc + 1) * 512);
      }
      int cb = (kc * 32 + q8) >> 3;
#pragma unroll
      for (int mf = 0; mf < 4; ++mf) {
        int r = wm * 64 + mf * 16 + col;
        bf16x8 a = *(const bf16x8*)(sh_h + r * 512 + swz(r, cb) * 8);
#pragma unroll
        for (int nf = 0; nf < 2; ++nf)
          acc3[mf][nf] = __builtin_amdgcn_mfma_f32_16x16x32_bf16(a, cur[nf], acc3[mf][nf], 0, 0, 0);
      }
    }
  }

  // ---- epilogue: write h (non-temporal) ----
  {
    int rq = q * 4;
#pragma unroll
    for (int mf = 0; mf < 4; ++mf)
#pragma unroll
      for (int nf = 0; nf < 2; ++nf) {
        int n = wn * 32 + nf * 16 + col;
        float bv = b3s[n];
#pragma unroll
        for (int i = 0; i < 4; ++i) {
          int r = wm * 64 + mf * 16 + rq + i;
          float v = fmaxf(acc3[mf][nf][i] + bv, 0.f);
          __builtin_nontemporal_store(v, out + HBASE + (blk * 128 + r) * 256 + n);
        }
      }
  }
}

extern "C" void kernel_launch(void* const* d_in, const int* in_sizes, int n_in,
                              void* d_out, int out_size, void* d_ws, size_t ws_size,
                              hipStream_t stream) {
  const float* in_feats = (const float*)d_in[0];
  const float* Wd = (const float*)d_in[1];
  const float* bd = (const float*)d_in[2];
  const float* W1 = (const float*)d_in[3];
  const float* b1 = (const float*)d_in[4];
  const float* W2 = (const float*)d_in[5];
  const float* b2 = (const float*)d_in[6];
  const float* W3 = (const float*)d_in[7];
  const float* b3 = (const float*)d_in[8];
  float* out = (float*)d_out;
  char* ws = (char*)d_ws;
  u16*   w2f = (u16*)(ws + WS_W2F);
  u16*   w3f = (u16*)(ws + WS_W3F);
  float* F1  = (float*)(ws + WS_F1);

  k_pre<<<512, 512, 0, stream>>>(in_feats, Wd, bd, W1, b1, W2, W3, w2f, w3f, F1, out);
  k_main<<<1024, 1024, 0, stream>>>(W1, b2, b3, w2f, w3f, F1, out);
}

// Round 9
// 266.216 us; speedup vs baseline: 1.1926x; 1.0034x over previous
//
#include <hip/hip_runtime.h>
#include <hip/hip_bf16.h>

typedef unsigned short u16;
typedef unsigned int   u32;

#define NP     4096
#define NCH    131072
#define HBASE  393216            // rel region = 131072*3
#define CLBASE 33947648          // HBASE + 131072*256

// ws layout (bytes)
#define WS_W2F   0               // 512 frags * 1KB  (W2 32x32x16: frag_id = nb*32 + kc)
#define WS_W3F   524288          // 256 frags * 1KB  (W3 32x32x16: frag_id = nb*32 + kc)
#define WS_F1    1048576         // [4096][512] f32

using bf16x8 = __attribute__((ext_vector_type(8))) short;
using f32x4  = __attribute__((ext_vector_type(4))) float;
using f32x16 = __attribute__((ext_vector_type(16))) float;

__device__ inline u32 pk2(float a, float b) {
  __hip_bfloat162 h = __float22bfloat162_rn(make_float2(a, b));
  return *reinterpret_cast<u32*>(&h);
}

// swizzle: 16B-slot index for (row r, col-group cg); bijective per row
__device__ inline int swz(int r, int cg) {
  return cg ^ (r & 7) ^ ((r >> 3) & 3);
}

// ================= K1: f1+rel / W-prep / cluster, merged ====================
__global__ __launch_bounds__(512, 2) void k_pre(const float* __restrict__ in_feats,
                                                const float* __restrict__ Wd,
                                                const float* __restrict__ bd,
                                                const float* __restrict__ W1,
                                                const float* __restrict__ b1,
                                                const float* __restrict__ W2,
                                                const float* __restrict__ W3,
                                                u16* __restrict__ w2f,
                                                u16* __restrict__ w3f,
                                                float* __restrict__ F1,
                                                float* __restrict__ out) {
  __shared__ __align__(16) char smem[69504];
  int b = blockIdx.x, tid = threadIdx.x;

  if (b < 256) {
    u16*   sh_a = (u16*)smem;
    float* b1s  = (float*)(smem + 8192);
    float* wdT  = (float*)(smem + 10240);        // [96][132]
    float* ne   = (float*)(smem + 60928);        // [16][128]
    float* bds  = (float*)(smem + 69120);
    int p0 = b * 16, lane = tid & 63, w = tid >> 6;
    b1s[tid] = b1[tid];
    if (tid < 96) bds[tid] = bd[tid];
    {
      int r = tid >> 5, k4 = (tid & 31) * 4;
      *(float4*)(ne + r * 128 + k4) = *(const float4*)(in_feats + (p0 + r) * 384 + k4);
    }
    {
      int r = tid >> 5, k0 = (tid & 31) * 8;
      const float4 v0 = *(const float4*)(in_feats + (p0 + r) * 384 + 128 + k0);
      const float4 v1 = *(const float4*)(in_feats + (p0 + r) * 384 + 128 + k0 + 4);
      uint4 o;
      o.x = pk2(v0.x, v0.y); o.y = pk2(v0.z, v0.w);
      o.z = pk2(v1.x, v1.y); o.w = pk2(v1.z, v1.w);
      int slot = (k0 >> 3) ^ (r & 7);
      *(uint4*)(sh_a + r * 256 + slot * 8) = o;
    }
    {
#pragma unroll
      for (int i = 0; i < 6; ++i) {
        int idx = i * 512 + tid;
        int k = idx / 24, c4 = (idx % 24) * 4;
        const float4 v = *(const float4*)(Wd + k * 96 + c4);
        wdT[(c4 + 0) * 132 + k] = v.x;
        wdT[(c4 + 1) * 132 + k] = v.y;
        wdT[(c4 + 2) * 132 + k] = v.z;
        wdT[(c4 + 3) * 132 + k] = v.w;
      }
    }
    __syncthreads();
#pragma unroll
    for (int j = 0; j < 3; ++j) {
      int u = j * 512 + tid;
      int p = u / 96, c = u - p * 96;
      const float4* nep = (const float4*)(ne + p * 128);
      const float4* wp  = (const float4*)(wdT + c * 132);
      float4 a4 = {0.f, 0.f, 0.f, 0.f};
#pragma unroll 8
      for (int kq = 0; kq < 32; ++kq) {
        const float4 av = nep[kq], bv = wp[kq];
        a4.x += av.x * bv.x; a4.y += av.y * bv.y;
        a4.z += av.z * bv.z; a4.w += av.w * bv.w;
      }
      out[(p0 + p) * 96 + c] = bds[c] + ((a4.x + a4.y) + (a4.z + a4.w));
    }
    f32x4 acc[4];
#pragma unroll
    for (int i = 0; i < 4; ++i) acc[i] = f32x4{0.f, 0.f, 0.f, 0.f};
    int col = lane & 15, q8 = (lane >> 4) * 8;
#pragma unroll
    for (int kc = 0; kc < 8; ++kc) {
      int slot = ((kc * 32 + q8) >> 3) ^ (col & 7);
      bf16x8 a = *(const bf16x8*)(sh_a + col * 256 + slot * 8);
#pragma unroll
      for (int nf = 0; nf < 4; ++nf) {
        const float* wp = W1 + (kc * 32 + q8) * 512 + (w * 4 + nf) * 16 + col;
        float v0 = wp[0],      v1 = wp[512],  v2 = wp[1024], v3 = wp[1536];
        float v4 = wp[2048],   v5 = wp[2560], v6 = wp[3072], v7 = wp[3584];
        union { bf16x8 v; u32 u[4]; } uu;
        uu.u[0] = pk2(v0, v1); uu.u[1] = pk2(v2, v3);
        uu.u[2] = pk2(v4, v5); uu.u[3] = pk2(v6, v7);
        acc[nf] = __builtin_amdgcn_mfma_f32_16x16x32_bf16(a, uu.v, acc[nf], 0, 0, 0);
      }
    }
    int rb = (lane >> 4) * 4;
#pragma unroll
    for (int nf = 0; nf < 4; ++nf) {
      int n = w * 64 + nf * 16 + col;
#pragma unroll
      for (int i = 0; i < 4; ++i)
        F1[(p0 + rb + i) * 512 + n] = acc[nf][i] + b1s[n];
    }
  } else if (b < 448) {
    // ---- W2/W3 -> bf16 32x32x16 fragment layout (2 tiles/block) ----
    // frag(nb,kc): lane l elem j -> W[k = kc*16 + (l>>5)*8 + j][n = nb*32 + (l&31)]
    float (*tile)[32][33] = (float (*)[32][33])smem;
    int h = tid >> 8, t = tid & 255;
    const float* src; u16* dst; int pitchN, g;
    if (b < 384) { g = (b - 256) * 2 + h; src = W2; dst = w2f; pitchN = 512; }
    else         { g = (b - 384) * 2 + h; src = W3; dst = w3f; pitchN = 256; }
    int kt = g & 15, nt = g >> 4;
    {
      int kk = t >> 3, n4 = (t & 7) * 4;
      const float4 v = *(const float4*)(src + (kt * 32 + kk) * pitchN + nt * 32 + n4);
      tile[h][kk][n4 + 0] = v.x; tile[h][kk][n4 + 1] = v.y;
      tile[h][kk][n4 + 2] = v.z; tile[h][kk][n4 + 3] = v.w;
    }
    __syncthreads();
    {
      int h2i = t >> 7, l = (t >> 1) & 63, half = t & 1;
      int kk = h2i * 16 + (l >> 5) * 8 + half * 4;
      int nn = l & 31;
      uint2 o;
      o.x = pk2(tile[h][kk + 0][nn], tile[h][kk + 1][nn]);
      o.y = pk2(tile[h][kk + 2][nn], tile[h][kk + 3][nn]);
      int frag_id = nt * 32 + kt * 2 + h2i;
      *(uint2*)(dst + frag_id * 512 + l * 8 + half * 4) = o;
    }
  } else {
    int idx = ((b - 448) * 512 + tid) * 4;
    float c = (float)(idx >> 5);
    float* p = out + CLBASE + idx;
    __builtin_nontemporal_store(c, p + 0);
    __builtin_nontemporal_store(c, p + 1);
    __builtin_nontemporal_store(c, p + 2);
    __builtin_nontemporal_store(c, p + 3);
  }
}

// ====== K2: h1-build + GEMM2 + GEMM3; 32x32x16 MFMA, A+B prefetch ===========
__global__ __launch_bounds__(1024) void k_main(const float* __restrict__ W1,
                                               const float* __restrict__ b2,
                                               const float* __restrict__ b3,
                                               const u16* __restrict__ w2f,
                                               const u16* __restrict__ w3f,
                                               const float* __restrict__ F1,
                                               float* __restrict__ out) {
  int blk = blockIdx.x;
  int tid = threadIdx.x, lane = tid & 63, w = tid >> 6;  // w in 0..15
  int wm = w >> 3, wn = w & 7;                           // 2 M-groups x 8 N-groups
  int r32 = lane & 31, kh = lane >> 5;
  __shared__ u16 sh_h[128 * 512];      // h1 then h2, swizzled 16B slots
  __shared__ float f1s[2048], w1bs[1536], b2s[512], b3s[256], rels[384];

  // ---- init loads ----
  if (tid < 512) *(float4*)(f1s + tid * 4) = *(const float4*)(F1 + blk * 2048 + tid * 4);
  if (tid < 768) *(float2*)(w1bs + tid * 2) = *(const float2*)(W1 + 131072 + tid * 2);
  if (tid < 512) b2s[tid] = b2[tid];
  if (tid >= 512 && tid < 768) b3s[tid - 512] = b3[tid - 512];
  if (tid >= 768 && tid < 960) {
    float2 rv = *(const float2*)(out + blk * 384 + (tid - 768) * 2);
    rels[(tid - 768) * 2 + 0] = rv.x;
    rels[(tid - 768) * 2 + 1] = rv.y;
  }
  __syncthreads();

  // ---- build h1 (128 x 512) into LDS as bf16; 16B writes ----
  {
    int row = tid >> 3, g = tid & 7, pp = row >> 5;
    float r0 = rels[row * 3 + 0], r1 = rels[row * 3 + 1], r2 = rels[row * 3 + 2];
#pragma unroll
    for (int j = 0; j < 8; ++j) {
      int c8 = g * 8 + j * 64;
      const float4 fa = *(const float4*)(f1s + pp * 512 + c8);
      const float4 fb = *(const float4*)(f1s + pp * 512 + c8 + 4);
      const float4 wa0 = *(const float4*)(w1bs + c8);
      const float4 wb0 = *(const float4*)(w1bs + c8 + 4);
      const float4 wa1 = *(const float4*)(w1bs + 512 + c8);
      const float4 wb1 = *(const float4*)(w1bs + 512 + c8 + 4);
      const float4 wa2 = *(const float4*)(w1bs + 1024 + c8);
      const float4 wb2 = *(const float4*)(w1bs + 1024 + c8 + 4);
      float v0 = fmaxf(fa.x + r0 * wa0.x + r1 * wa1.x + r2 * wa2.x, 0.f);
      float v1 = fmaxf(fa.y + r0 * wa0.y + r1 * wa1.y + r2 * wa2.y, 0.f);
      float v2 = fmaxf(fa.z + r0 * wa0.z + r1 * wa1.z + r2 * wa2.z, 0.f);
      float v3 = fmaxf(fa.w + r0 * wa0.w + r1 * wa1.w + r2 * wa2.w, 0.f);
      float v4 = fmaxf(fb.x + r0 * wb0.x + r1 * wb1.x + r2 * wb2.x, 0.f);
      float v5 = fmaxf(fb.y + r0 * wb0.y + r1 * wb1.y + r2 * wb2.y, 0.f);
      float v6 = fmaxf(fb.z + r0 * wb0.z + r1 * wb1.z + r2 * wb2.z, 0.f);
      float v7 = fmaxf(fb.w + r0 * wb0.w + r1 * wb1.w + r2 * wb2.w, 0.f);
      uint4 o;
      o.x = pk2(v0, v1); o.y = pk2(v2, v3);
      o.z = pk2(v4, v5); o.w = pk2(v6, v7);
      *(uint4*)(sh_h + row * 512 + swz(row, c8 >> 3) * 8) = o;
    }
  }
  __syncthreads();

  // A-row constants
  int arow0 = wm * 64 + r32, arow1 = arow0 + 32;
  int ax0 = (arow0 & 7) ^ ((arow0 >> 3) & 3);
  int ax1 = (arow1 & 7) ^ ((arow1 >> 3) & 3);
  const u16* a0base = sh_h + arow0 * 512;
  const u16* a1base = sh_h + arow1 * 512;

#define LDA0(ks) (*(const bf16x8*)(a0base + ((((ks) * 2 + kh) ^ ax0) << 3)))
#define LDA1(ks) (*(const bf16x8*)(a1base + ((((ks) * 2 + kh) ^ ax1) << 3)))

  // ---- GEMM2: h2 = relu(h1 @ W2 + b2); 32x32x16, A+B prefetch ----
  f32x16 acc2[2][2];
#pragma unroll
  for (int mt = 0; mt < 2; ++mt)
#pragma unroll
    for (int nt = 0; nt < 2; ++nt)
#pragma unroll
      for (int i = 0; i < 16; ++i) acc2[mt][nt][i] = 0.f;
  {
    const u16* w2p = w2f + (size_t)(wn * 2) * 32 * 512 + lane * 8;
    bf16x8 A0[2], A1[2], B0[2], B1[2];
    A0[0] = LDA0(0); A0[1] = LDA1(0);
    B0[0] = *(const bf16x8*)(w2p);
    B0[1] = *(const bf16x8*)(w2p + 32 * 512);
#pragma unroll
    for (int ks = 0; ks < 32; ks += 2) {
      A1[0] = LDA0(ks + 1); A1[1] = LDA1(ks + 1);
      B1[0] = *(const bf16x8*)(w2p + (ks + 1) * 512);
      B1[1] = *(const bf16x8*)(w2p + (32 + ks + 1) * 512);
      acc2[0][0] = __builtin_amdgcn_mfma_f32_32x32x16_bf16(A0[0], B0[0], acc2[0][0], 0, 0, 0);
      acc2[0][1] = __builtin_amdgcn_mfma_f32_32x32x16_bf16(A0[0], B0[1], acc2[0][1], 0, 0, 0);
      acc2[1][0] = __builtin_amdgcn_mfma_f32_32x32x16_bf16(A0[1], B0[0], acc2[1][0], 0, 0, 0);
      acc2[1][1] = __builtin_amdgcn_mfma_f32_32x32x16_bf16(A0[1], B0[1], acc2[1][1], 0, 0, 0);
      if (ks + 2 < 32) {
        A0[0] = LDA0(ks + 2); A0[1] = LDA1(ks + 2);
        B0[0] = *(const bf16x8*)(w2p + (ks + 2) * 512);
        B0[1] = *(const bf16x8*)(w2p + (32 + ks + 2) * 512);
      }
      acc2[0][0] = __builtin_amdgcn_mfma_f32_32x32x16_bf16(A1[0], B1[0], acc2[0][0], 0, 0, 0);
      acc2[0][1] = __builtin_amdgcn_mfma_f32_32x32x16_bf16(A1[0], B1[1], acc2[0][1], 0, 0, 0);
      acc2[1][0] = __builtin_amdgcn_mfma_f32_32x32x16_bf16(A1[1], B1[0], acc2[1][0], 0, 0, 0);
      acc2[1][1] = __builtin_amdgcn_mfma_f32_32x32x16_bf16(A1[1], B1[1], acc2[1][1], 0, 0, 0);
    }
  }
  __syncthreads();   // all h1 reads done

  // ---- h2 -> LDS (relu + bf16); C-layout: col=lane&31, row=(i&3)+8*(i>>2)+4*kh
  {
#pragma unroll
    for (int mt = 0; mt < 2; ++mt)
#pragma unroll
      for (int nt = 0; nt < 2; ++nt) {
        int n = wn * 64 + nt * 32 + r32, cg = n >> 3, n7 = n & 7;
        float bv = b2s[n];
#pragma unroll
        for (int i = 0; i < 16; i += 2) {
          int rin = (i & 3) + 8 * (i >> 2) + 4 * kh;
          int ra = wm * 64 + mt * 32 + rin, rb = ra + 1;
          u32 p = pk2(fmaxf(acc2[mt][nt][i] + bv, 0.f),
                      fmaxf(acc2[mt][nt][i + 1] + bv, 0.f));
          sh_h[ra * 512 + swz(ra, cg) * 8 + n7] = (u16)(p & 0xffff);
          sh_h[rb * 512 + swz(rb, cg) * 8 + n7] = (u16)(p >> 16);
        }
      }
  }
  __syncthreads();

  // ---- GEMM3: h3 = relu(h2 @ W3 + b3); 32x32x16, A+B prefetch ----
  f32x16 acc3[2];
#pragma unroll
  for (int mt = 0; mt < 2; ++mt)
#pragma unroll
    for (int i = 0; i < 16; ++i) acc3[mt][i] = 0.f;
  {
    const u16* w3p = w3f + (size_t)(wn) * 32 * 512 + lane * 8;
    bf16x8 A0[2], A1[2], B0, B1;
    A0[0] = LDA0(0); A0[1] = LDA1(0);
    B0 = *(const bf16x8*)(w3p);
#pragma unroll
    for (int ks = 0; ks < 32; ks += 2) {
      A1[0] = LDA0(ks + 1); A1[1] = LDA1(ks + 1);
      B1 = *(const bf16x8*)(w3p + (ks + 1) * 512);
      acc3[0] = __builtin_amdgcn_mfma_f32_32x32x16_bf16(A0[0], B0, acc3[0], 0, 0, 0);
      acc3[1] = __builtin_amdgcn_mfma_f32_32x32x16_bf16(A0[1], B0, acc3[1], 0, 0, 0);
      if (ks + 2 < 32) {
        A0[0] = LDA0(ks + 2); A0[1] = LDA1(ks + 2);
        B0 = *(const bf16x8*)(w3p + (ks + 2) * 512);
      }
      acc3[0] = __builtin_amdgcn_mfma_f32_32x32x16_bf16(A1[0], B1, acc3[0], 0, 0, 0);
      acc3[1] = __builtin_amdgcn_mfma_f32_32x32x16_bf16(A1[1], B1, acc3[1], 0, 0, 0);
    }
  }

  // ---- epilogue: write h (non-temporal) ----
  {
    int n = wn * 32 + r32;
    float bv = b3s[n];
#pragma unroll
    for (int mt = 0; mt < 2; ++mt)
#pragma unroll
      for (int i = 0; i < 16; ++i) {
        int rin = (i & 3) + 8 * (i >> 2) + 4 * kh;
        int r = wm * 64 + mt * 32 + rin;
        float v = fmaxf(acc3[mt][i] + bv, 0.f);
        __builtin_nontemporal_store(v, out + HBASE + (blk * 128 + r) * 256 + n);
      }
  }
#undef LDA0
#undef LDA1
}

extern "C" void kernel_launch(void* const* d_in, const int* in_sizes, int n_in,
                              void* d_out, int out_size, void* d_ws, size_t ws_size,
                              hipStream_t stream) {
  const float* in_feats = (const float*)d_in[0];
  const float* Wd = (const float*)d_in[1];
  const float* bd = (const float*)d_in[2];
  const float* W1 = (const float*)d_in[3];
  const float* b1 = (const float*)d_in[4];
  const float* W2 = (const float*)d_in[5];
  const float* b2 = (const float*)d_in[6];
  const float* W3 = (const float*)d_in[7];
  const float* b3 = (const float*)d_in[8];
  float* out = (float*)d_out;
  char* ws = (char*)d_ws;
  u16*   w2f = (u16*)(ws + WS_W2F);
  u16*   w3f = (u16*)(ws + WS_W3F);
  float* F1  = (float*)(ws + WS_F1);

  k_pre<<<512, 512, 0, stream>>>(in_feats, Wd, bd, W1, b1, W2, W3, w2f, w3f, F1, out);
  k_main<<<1024, 1024, 0, stream>>>(W1, b2, b3, w2f, w3f, F1, out);
}